// Round 11
// baseline (323.115 us; speedup 1.0000x reference)
//
#include <hip/hip_runtime.h>
#include <hip/hip_bf16.h>

#define NEG_SLOPE 0.2f

// ---------------------------------------------------------------------------
// f32 GEMM, BM=128 BN=128 BK=16, 256 threads, 8x8 micro-tile. (R9 win)
// ---------------------------------------------------------------------------
__global__ __launch_bounds__(256) void gemm_big(
    const float* __restrict__ A,
    const float* __restrict__ W0, const float* __restrict__ W1, const float* __restrict__ W2,
    const float* __restrict__ b0, const float* __restrict__ b1, const float* __restrict__ b2,
    float* __restrict__ D0, float* __restrict__ D1, float* __restrict__ D2,
    int V, int lrelu)
{
    __shared__ float As[16][136];   // [k][row], 8.7 KB
    __shared__ float Bs[16][192];   // [k][col-block*12], 12 KB

    const int m = blockIdx.y;
    const float* __restrict__ W  = (m == 0) ? W0 : ((m == 1) ? W1 : W2);
    const float* __restrict__ bb = (m == 0) ? b0 : ((m == 1) ? b1 : b2);
    float* __restrict__ D        = (m == 0) ? D0 : ((m == 1) ? D1 : D2);

    const int tid = threadIdx.x;
    const int tx = tid & 15;
    const int ty = tid >> 4;
    const int row0 = blockIdx.x * 128;

    const int ar = tid >> 1;
    const int ak = (tid & 1) * 8;
    const int bk = tid >> 4;
    const int bc = tid & 15;

    float acc[8][8];
#pragma unroll
    for (int i = 0; i < 8; ++i)
#pragma unroll
        for (int j = 0; j < 8; ++j) acc[i][j] = 0.f;

    for (int k0 = 0; k0 < 128; k0 += 16) {
        {
            const int gr = row0 + ar;
            float4 a0 = make_float4(0.f, 0.f, 0.f, 0.f);
            float4 a1 = make_float4(0.f, 0.f, 0.f, 0.f);
            if (gr < V) {
                a0 = *(const float4*)(A + (size_t)gr * 128 + k0 + ak);
                a1 = *(const float4*)(A + (size_t)gr * 128 + k0 + ak + 4);
            }
            As[ak + 0][ar] = a0.x; As[ak + 1][ar] = a0.y;
            As[ak + 2][ar] = a0.z; As[ak + 3][ar] = a0.w;
            As[ak + 4][ar] = a1.x; As[ak + 5][ar] = a1.y;
            As[ak + 6][ar] = a1.z; As[ak + 7][ar] = a1.w;
        }
        {
            const float4 w0 = *(const float4*)(W + (size_t)(k0 + bk) * 128 + bc * 8);
            const float4 w1 = *(const float4*)(W + (size_t)(k0 + bk) * 128 + bc * 8 + 4);
            *(float4*)&Bs[bk][bc * 12]     = w0;
            *(float4*)&Bs[bk][bc * 12 + 4] = w1;
        }
        __syncthreads();
#pragma unroll
        for (int kk = 0; kk < 16; ++kk) {
            float a[8], b[8];
            *(float4*)&a[0] = *(const float4*)&As[kk][ty * 8];
            *(float4*)&a[4] = *(const float4*)&As[kk][ty * 8 + 4];
            *(float4*)&b[0] = *(const float4*)&Bs[kk][tx * 12];
            *(float4*)&b[4] = *(const float4*)&Bs[kk][tx * 12 + 4];
#pragma unroll
            for (int i = 0; i < 8; ++i)
#pragma unroll
                for (int j = 0; j < 8; ++j) acc[i][j] = fmaf(a[i], b[j], acc[i][j]);
        }
        __syncthreads();
    }

#pragma unroll
    for (int i = 0; i < 8; ++i) {
        const int gr = row0 + ty * 8 + i;
        if (gr >= V) continue;
#pragma unroll
        for (int j = 0; j < 8; j += 4) {
            float4 o;
            float* op = &o.x;
#pragma unroll
            for (int jj = 0; jj < 4; ++jj) {
                float x = acc[i][j + jj] + bb[tx * 8 + j + jj];
                if (lrelu) x = (x > 0.f) ? x : NEG_SLOPE * x;
                op[jj] = x;
            }
            *(float4*)(D + (size_t)gr * 128 + tx * 8 + j) = o;
        }
    }
}

// ---------------------------------------------------------------------------
// Per-target in-degree count
// ---------------------------------------------------------------------------
__global__ __launch_bounds__(256) void count_tgt(const int* __restrict__ tgt,
                                                 int* __restrict__ cnt, int E)
{
    const int e = blockIdx.x * blockDim.x + threadIdx.x;
    if (e < E) atomicAdd(cnt + tgt[e], 1);
}

// ---------------------------------------------------------------------------
// CSR build: block-wise exclusive scan of per-node counts
// ---------------------------------------------------------------------------
__global__ __launch_bounds__(256) void scan1(const int* __restrict__ cnt,
                                             int* __restrict__ offs,
                                             int* __restrict__ bsums, int V)
{
    __shared__ int sh[256];
    const int t = threadIdx.x;
    const int base = blockIdx.x * 1024;
    int v[4];
    int s = 0;
#pragma unroll
    for (int i = 0; i < 4; ++i) {
        const int idx = base + t * 4 + i;
        v[i] = (idx < V) ? cnt[idx] : 0;
        s += v[i];
    }
    sh[t] = s;
    __syncthreads();
    for (int off = 1; off < 256; off <<= 1) {
        const int x = (t >= off) ? sh[t - off] : 0;
        __syncthreads();
        sh[t] += x;
        __syncthreads();
    }
    int run = (t > 0) ? sh[t - 1] : 0;
#pragma unroll
    for (int i = 0; i < 4; ++i) {
        const int idx = base + t * 4 + i;
        if (idx < V) offs[idx] = run;
        run += v[i];
    }
    if (t == 255) bsums[blockIdx.x] = sh[255];
}

__global__ void scan2(int* __restrict__ bsums, int nb)
{
    if (threadIdx.x == 0 && blockIdx.x == 0) {
        int run = 0;
        for (int i = 0; i < nb; ++i) { const int x = bsums[i]; bsums[i] = run; run += x; }
    }
}

__global__ __launch_bounds__(256) void scan3(int* __restrict__ offs,
                                             const int* __restrict__ bsums,
                                             int* __restrict__ fill, int V)
{
    const int v = blockIdx.x * blockDim.x + threadIdx.x;
    if (v >= V) return;
    const int o = offs[v] + bsums[v >> 10];
    offs[v] = o;
    fill[v] = o;
}

// ---------------------------------------------------------------------------
// Scatter edges into target-sorted order: packed (src, edge weight) int2.
// ---------------------------------------------------------------------------
__global__ __launch_bounds__(256) void scatter_edges(
    const int* __restrict__ src, const int* __restrict__ tgt,
    const float* __restrict__ ew, int* __restrict__ fill,
    int2* __restrict__ se, int E)
{
    const int e = blockIdx.x * blockDim.x + threadIdx.x;
    if (e >= E) return;
    const int pos = atomicAdd(fill + tgt[e], 1);
    se[pos] = make_int2(src[e], __float_as_int(ew[e]));
}

// ---------------------------------------------------------------------------
// HEAD-SPLIT fused kernel: one wave = one (node, head). Block = 4 nodes x
// SAME head; bid = chunk*4 + head. With round-robin bid->XCD dispatch,
// XCD j processes ONLY head j%4, shrinking its Q/Vv gather footprint
// 25.6 MB -> 6.4 MB (~L2-sized) [R10 diagnosis: fused_agg is L2-miss-rate
// bound at ~3.3 TB/s FETCH; scheduling changes were all neutral].
// Gathers are 128 B cacheline-aligned head slices. K slice lives in VGPRs
// (no LDS). Stage A: lane = e*4+i computes quarter-dot of edge e; 2-step
// shfl reduce. Stage B: lane = grp*16+d, 4 edges in flight per iteration.
// deg via full-wave butterfly (each p counted 4x, exact /4).
// ---------------------------------------------------------------------------
__global__ __launch_bounds__(256) void fused_agg_h(
    const float* __restrict__ Q, const float* __restrict__ K,
    const float* __restrict__ Vv, const int2* __restrict__ se,
    const int* __restrict__ offs, const int* __restrict__ fill,
    const float* __restrict__ Wei, const float* __restrict__ bei,
    float* __restrict__ accum, int V)
{
    const int head  = blockIdx.x & 3;
    const int chunk = blockIdx.x >> 2;
    const int wid   = threadIdx.x >> 6;
    const int node  = chunk * 4 + wid;
    if (node >= V) return;
    const int l   = threadIdx.x & 63;
    const int eg  = l >> 2;     // stage-A edge slot 0..15
    const int qi  = l & 3;      // quarter-dot index 0..3
    const int grp = l >> 4;     // stage-B edge group 0..3
    const int d   = l & 15;     // stage-B dim pair 0..15

    // K head-slice into regs (dims qi*8 .. +8); same 32B per 4-lane group
    const float4* kp = (const float4*)(K + (size_t)node * 128 + head * 32);
    const float4 k0 = kp[qi * 2];
    const float4 k1 = kp[qi * 2 + 1];

    const float weH = Wei[head], beH = bei[head];

    int b0 = offs[node];
    const int e0 = fill[node];

    float degacc = 0.f;        // each p counted 4x
    float ax = 0.f, ay = 0.f;  // partial over this grp's edge subset

    for (; b0 < e0; b0 += 16) {
        const int nj = min(16, e0 - b0);
        // lanes 0..15 load se; broadcast to 4-lane groups
        int s_raw = 0; float w_raw = 0.f;
        if (l < nj) {
            const int2 t = se[b0 + l];
            s_raw = t.x; w_raw = __int_as_float(t.y);
        }
        const int   s = __shfl(s_raw, eg);
        const float w = __shfl(w_raw, eg);

        float p = 0.f;
        {
            const float4* qp = (const float4*)(Q + (size_t)s * 128 + head * 32);
            const float4 q0 = qp[qi * 2];
            const float4 q1 = qp[qi * 2 + 1];
            float dot = q0.x * k0.x + q0.y * k0.y + q0.z * k0.z + q0.w * k0.w
                      + q1.x * k1.x + q1.y * k1.y + q1.z * k1.z + q1.w * k1.w;
            dot += __shfl_xor(dot, 1);
            dot += __shfl_xor(dot, 2);
            if (eg < nj) {
                float bb = fmaf(w, weH, beH);
                bb = (bb > 0.f) ? bb : NEG_SLOPE * bb;
                p = __expf(fmaf(dot, 0.17677669529663687f, bb));
            }
        }
        degacc += p;
        const float coef = p * w;   // valid at all 4 lanes of edge eg

        // stage B: grp g handles edge j+g; 4 edges (4 cachelines) in flight
        for (int j = 0; j < nj; j += 4) {
            const int   e  = j + grp;          // may exceed nj-1 -> coef=0, s=0
            const float cj = __shfl(coef, e * 4);
            const int   sj = __shfl(s,    e * 4);
            const float2 v = *(const float2*)(Vv + (size_t)sj * 128 + head * 32 + d * 2);
            ax = fmaf(cj, v.x, ax);
            ay = fmaf(cj, v.y, ay);
        }
    }

    // combine grp partials (same d across grps)
    ax += __shfl_xor(ax, 16); ax += __shfl_xor(ax, 32);
    ay += __shfl_xor(ay, 16); ay += __shfl_xor(ay, 32);
    // deg: full-wave butterfly; every p counted 4x -> exact /4
    float dg = degacc;
    dg += __shfl_xor(dg, 1);  dg += __shfl_xor(dg, 2);
    dg += __shfl_xor(dg, 4);  dg += __shfl_xor(dg, 8);
    dg += __shfl_xor(dg, 16); dg += __shfl_xor(dg, 32);
    const float inv = 1.0f / (dg * 0.25f + 1e-16f);

    if (grp == 0)
        *(float2*)(accum + (size_t)node * 128 + head * 32 + d * 2) =
            make_float2(ax * inv, ay * inv);
}

// ---------------------------------------------------------------------------
extern "C" void kernel_launch(void* const* d_in, const int* in_sizes, int n_in,
                              void* d_out, int out_size, void* d_ws, size_t ws_size,
                              hipStream_t stream)
{
    const float* h   = (const float*)d_in[0];
    const int*   ei  = (const int*)  d_in[1];
    const float* ew  = (const float*)d_in[2];
    const float* Wq  = (const float*)d_in[3];
    const float* bq  = (const float*)d_in[4];
    const float* Wk  = (const float*)d_in[5];
    const float* bk  = (const float*)d_in[6];
    const float* Wv  = (const float*)d_in[7];
    const float* bv  = (const float*)d_in[8];
    const float* Wo  = (const float*)d_in[9];
    const float* bo  = (const float*)d_in[10];
    const float* Wei = (const float*)d_in[11];
    const float* bei = (const float*)d_in[12];

    const int V = in_sizes[0] / 128;
    const int E = in_sizes[2];
    const int* src = ei;
    const int* tgt = ei + E;

    // workspace layout
    float* Q     = (float*)d_ws;
    float* Km    = Q  + (size_t)V * 128;
    float* Vm    = Km + (size_t)V * 128;
    float* accum = Vm + (size_t)V * 128;
    int2*  se    = (int2*)(accum + (size_t)V * 128);
    int*   cnt   = (int*)(se + E);
    int*   offs  = cnt  + V;
    int*   fill  = offs + V + 1;
    int*   bsums = fill + V;

    hipMemsetAsync(cnt, 0, (size_t)V * sizeof(int), stream);

    const int bigGrid = (V + 127) / 128;
    gemm_big<<<dim3(bigGrid, 3), 256, 0, stream>>>(
        h, Wq, Wk, Wv, bq, bk, bv, Q, Km, Vm, V, 0);

    count_tgt<<<(E + 255) / 256, 256, 0, stream>>>(tgt, cnt, E);
    const int nb = (V + 1023) / 1024;
    scan1<<<nb, 256, 0, stream>>>(cnt, offs, bsums, V);
    scan2<<<1, 64, 0, stream>>>(bsums, nb);
    scan3<<<(V + 255) / 256, 256, 0, stream>>>(offs, bsums, fill, V);
    scatter_edges<<<(E + 255) / 256, 256, 0, stream>>>(
        src, tgt, ew, fill, se, E);

    // one wave per (node, head); block = 4 nodes x same head;
    // bid = chunk*4 + head -> XCD j (bid%8 round-robin) sees only head j%4
    const int chunks = (V + 3) / 4;
    fused_agg_h<<<chunks * 4, 256, 0, stream>>>(
        Q, Km, Vm, se, offs, fill, Wei, bei, accum, V);

    gemm_big<<<dim3(bigGrid, 1), 256, 0, stream>>>(
        accum, Wo, Wo, Wo, bo, bo, bo, (float*)d_out, (float*)d_out, (float*)d_out, V, 1);
}

// Round 12
// 294.687 us; speedup vs baseline: 1.0965x; 1.0965x over previous
//
#include <hip/hip_runtime.h>
#include <hip/hip_bf16.h>

#define NEG_SLOPE 0.2f

typedef __attribute__((ext_vector_type(8))) short bf16x8;
typedef __attribute__((ext_vector_type(4))) float f32x4;

// split f32 -> bf16 hi + bf16 lo (RNE both); x ~= hi + lo with ~2^-17 residual
__device__ __forceinline__ void splitf(float x, unsigned short& h, unsigned short& l)
{
    const unsigned int u  = __float_as_uint(x);
    const unsigned int uh = (u + 0x7fffu + ((u >> 16) & 1u)) >> 16;
    const float        fh = __uint_as_float(uh << 16);
    const float        r  = x - fh;
    const unsigned int ur = __float_as_uint(r);
    const unsigned int ul = (ur + 0x7fffu + ((ur >> 16) & 1u)) >> 16;
    h = (unsigned short)uh;
    l = (unsigned short)ul;
}

// ---------------------------------------------------------------------------
// Pre-split + pre-transpose a 128x128 weight: W[k][n] f32 -> Wt_hi/lo[n][k] bf16
// ---------------------------------------------------------------------------
__global__ __launch_bounds__(256) void wsplit(const float* __restrict__ W,
                                              unsigned short* __restrict__ Wth,
                                              unsigned short* __restrict__ Wtl)
{
    const int t = blockIdx.x * 256 + threadIdx.x;   // 0..16383, grid=64
    const int k = t >> 7, n = t & 127;
    unsigned short h, l;
    splitf(W[k * 128 + n], h, l);
    Wth[n * 128 + k] = h;
    Wtl[n * 128 + k] = l;
}

// ---------------------------------------------------------------------------
// Split-precision MFMA GEMM: D[V,128] = act(A[V,128] @ W + bias).
// A*B ~= Ah*Bh + Ah*Bl + Al*Bh (bf16 hi/lo RNE split, f32 MFMA accum);
// dropped lo*lo ~ 2^-17 relative -- meets the 7e-5 bar (R7/R11 analysis).
// BM=64 (4 waves x 16 rows), BN=128, BK=32 (one 16x16x32 k-step per ldst).
// A split in-LDS at staging (no extra HBM); W pre-split/transposed (wsplit).
// LDS rows padded to 40 shorts (80B): frag reads/writes 2-way max (free).
// Frag layout (cdna4 docs): A row=lane&15, kchunk=lane>>4; B col=lane&15;
// C/D col=lane&15, row=(lane>>4)*4+reg.
// ---------------------------------------------------------------------------
__global__ __launch_bounds__(256) void gemm_mfma(
    const float* __restrict__ A,
    const unsigned short* __restrict__ Bh0, const unsigned short* __restrict__ Bl0,
    const unsigned short* __restrict__ Bh1, const unsigned short* __restrict__ Bl1,
    const unsigned short* __restrict__ Bh2, const unsigned short* __restrict__ Bl2,
    const float* __restrict__ b0, const float* __restrict__ b1, const float* __restrict__ b2,
    float* __restrict__ D0, float* __restrict__ D1, float* __restrict__ D2,
    int V, int lrelu)
{
    __shared__ unsigned short Ash[64][40], Asl[64][40];     // 10 KB
    __shared__ unsigned short Bsh[128][40], Bsl[128][40];   // 20 KB

    const int m = blockIdx.y;
    const unsigned short* __restrict__ Wth = (m == 0) ? Bh0 : ((m == 1) ? Bh1 : Bh2);
    const unsigned short* __restrict__ Wtl = (m == 0) ? Bl0 : ((m == 1) ? Bl1 : Bl2);
    const float* __restrict__ bias         = (m == 0) ? b0  : ((m == 1) ? b1  : b2);
    float* __restrict__ D                  = (m == 0) ? D0  : ((m == 1) ? D1  : D2);

    const int tid  = threadIdx.x;
    const int w    = tid >> 6;
    const int l    = tid & 63;
    const int row0 = blockIdx.x * 64;

    const int srow = tid >> 2;      // A staging: row 0..63
    const int skc  = tid & 3;       // A staging: k-chunk 0..3

    f32x4 acc[8];
#pragma unroll
    for (int t = 0; t < 8; ++t) acc[t] = (f32x4){0.f, 0.f, 0.f, 0.f};

    for (int k0 = 0; k0 < 128; k0 += 32) {
        // stage A (64 rows x 32 k), f32 -> hi/lo bf16
        {
            const int gr = row0 + srow;
            float x[8] = {0.f, 0.f, 0.f, 0.f, 0.f, 0.f, 0.f, 0.f};
            if (gr < V) {
                const float4 a0 = *(const float4*)(A + (size_t)gr * 128 + k0 + skc * 8);
                const float4 a1 = *(const float4*)(A + (size_t)gr * 128 + k0 + skc * 8 + 4);
                x[0] = a0.x; x[1] = a0.y; x[2] = a0.z; x[3] = a0.w;
                x[4] = a1.x; x[5] = a1.y; x[6] = a1.z; x[7] = a1.w;
            }
            bf16x8 vh, vl;
#pragma unroll
            for (int i = 0; i < 8; ++i) {
                unsigned short hh, ll;
                splitf(x[i], hh, ll);
                vh[i] = (short)hh; vl[i] = (short)ll;
            }
            *(bf16x8*)&Ash[srow][skc * 8] = vh;
            *(bf16x8*)&Asl[srow][skc * 8] = vl;
        }
        // stage B (128 cols x 32 k) from pre-split transposed weights
#pragma unroll
        for (int r = 0; r < 2; ++r) {
            const int idx = tid + r * 256;
            const int n = idx >> 2, bkc = idx & 3;
            *(bf16x8*)&Bsh[n][bkc * 8] = *(const bf16x8*)(Wth + n * 128 + k0 + bkc * 8);
            *(bf16x8*)&Bsl[n][bkc * 8] = *(const bf16x8*)(Wtl + n * 128 + k0 + bkc * 8);
        }
        __syncthreads();

        const int ar  = w * 16 + (l & 15);
        const int kc8 = (l >> 4) * 8;
        const bf16x8 ah = *(const bf16x8*)&Ash[ar][kc8];
        const bf16x8 al = *(const bf16x8*)&Asl[ar][kc8];
#pragma unroll
        for (int t = 0; t < 8; ++t) {
            const int col = t * 16 + (l & 15);
            const bf16x8 bh = *(const bf16x8*)&Bsh[col][kc8];
            const bf16x8 bl = *(const bf16x8*)&Bsl[col][kc8];
            acc[t] = __builtin_amdgcn_mfma_f32_16x16x32_bf16(ah, bh, acc[t], 0, 0, 0);
            acc[t] = __builtin_amdgcn_mfma_f32_16x16x32_bf16(ah, bl, acc[t], 0, 0, 0);
            acc[t] = __builtin_amdgcn_mfma_f32_16x16x32_bf16(al, bh, acc[t], 0, 0, 0);
        }
        __syncthreads();
    }

    // epilogue: bias + optional lrelu; C/D frag col=lane&15, row=(lane>>4)*4+r
    const int colb = l & 15;
    const int rsub = (l >> 4) * 4;
#pragma unroll
    for (int t = 0; t < 8; ++t) {
        const int col = t * 16 + colb;
        const float bv = bias[col];
#pragma unroll
        for (int r = 0; r < 4; ++r) {
            const int grow = row0 + w * 16 + rsub + r;
            if (grow < V) {
                float xx = acc[t][r] + bv;
                if (lrelu) xx = (xx > 0.f) ? xx : NEG_SLOPE * xx;
                D[(size_t)grow * 128 + col] = xx;
            }
        }
    }
}

// ---------------------------------------------------------------------------
// Per-target in-degree count
// ---------------------------------------------------------------------------
__global__ __launch_bounds__(256) void count_tgt(const int* __restrict__ tgt,
                                                 int* __restrict__ cnt, int E)
{
    const int e = blockIdx.x * blockDim.x + threadIdx.x;
    if (e < E) atomicAdd(cnt + tgt[e], 1);
}

// ---------------------------------------------------------------------------
// CSR build: block-wise exclusive scan of per-node counts
// ---------------------------------------------------------------------------
__global__ __launch_bounds__(256) void scan1(const int* __restrict__ cnt,
                                             int* __restrict__ offs,
                                             int* __restrict__ bsums, int V)
{
    __shared__ int sh[256];
    const int t = threadIdx.x;
    const int base = blockIdx.x * 1024;
    int v[4];
    int s = 0;
#pragma unroll
    for (int i = 0; i < 4; ++i) {
        const int idx = base + t * 4 + i;
        v[i] = (idx < V) ? cnt[idx] : 0;
        s += v[i];
    }
    sh[t] = s;
    __syncthreads();
    for (int off = 1; off < 256; off <<= 1) {
        const int x = (t >= off) ? sh[t - off] : 0;
        __syncthreads();
        sh[t] += x;
        __syncthreads();
    }
    int run = (t > 0) ? sh[t - 1] : 0;
#pragma unroll
    for (int i = 0; i < 4; ++i) {
        const int idx = base + t * 4 + i;
        if (idx < V) offs[idx] = run;
        run += v[i];
    }
    if (t == 255) bsums[blockIdx.x] = sh[255];
}

__global__ void scan2(int* __restrict__ bsums, int nb)
{
    if (threadIdx.x == 0 && blockIdx.x == 0) {
        int run = 0;
        for (int i = 0; i < nb; ++i) { const int x = bsums[i]; bsums[i] = run; run += x; }
    }
}

__global__ __launch_bounds__(256) void scan3(int* __restrict__ offs,
                                             const int* __restrict__ bsums,
                                             int* __restrict__ fill, int V)
{
    const int v = blockIdx.x * blockDim.x + threadIdx.x;
    if (v >= V) return;
    const int o = offs[v] + bsums[v >> 10];
    offs[v] = o;
    fill[v] = o;
}

// ---------------------------------------------------------------------------
// Scatter edges into target-sorted order: packed (src, edge weight) int2.
// ---------------------------------------------------------------------------
__global__ __launch_bounds__(256) void scatter_edges(
    const int* __restrict__ src, const int* __restrict__ tgt,
    const float* __restrict__ ew, int* __restrict__ fill,
    int2* __restrict__ se, int E)
{
    const int e = blockIdx.x * blockDim.x + threadIdx.x;
    if (e >= E) return;
    const int pos = atomicAdd(fill + tgt[e], 1);
    se[pos] = make_int2(src[e], __float_as_int(ew[e]));
}

// ---------------------------------------------------------------------------
// Fused per-node kernel (all f32): QK^T + exp + denom + weighted Vv
// aggregation + normalization. One wave per node, STATIC mapping -- R11
// verdict: best of 5 scheduling variants (119 us); head-split cut FETCH 18%
// but added VALU overhead; grid-stride lost locality; atomics serialize.
// Ksh padded [4][36]: conflict-free b128 broadcast reads.
// ---------------------------------------------------------------------------
__global__ __launch_bounds__(256) void fused_agg(
    const float* __restrict__ Q, const float* __restrict__ K,
    const float* __restrict__ Vv, const int2* __restrict__ se,
    const int* __restrict__ offs, const int* __restrict__ fill,
    const float* __restrict__ Wei, const float* __restrict__ bei,
    float* __restrict__ accum, int V)
{
    __shared__ float Ksh[4][4][36];   // [wave][head][32 padded to 36]
    const int wid = threadIdx.x >> 6;
    const int node = blockIdx.x * 4 + wid;
    if (node >= V) return;
    const int l   = threadIdx.x & 63;
    const int h   = l & 3;    // stage-A head (lane = jj*4 + h)
    const int hd  = l >> 4;   // stage-B head (lane owns dims 2l,2l+1)
    const float weH = Wei[h], beH = bei[h];
    const float2* __restrict__ Vv2 = (const float2*)Vv;

    {
        const float2 kk = *(const float2*)(K + (size_t)node * 128 + l * 2);
        const int f0 = l * 2;
        Ksh[wid][f0 >> 5][f0 & 31] = kk.x;
        Ksh[wid][(f0 + 1) >> 5][(f0 + 1) & 31] = kk.y;
    }

    const int start = offs[node];
    const int end   = fill[node];

    float degacc = 0.f;
    float ax = 0.f, ay = 0.f;

    for (int b0 = start; b0 < end; b0 += 16) {
        const int nj = min(16, end - b0);
        const int jj = l >> 2;
        int   s = 0;
        float w = 0.f, p = 0.f;
        if (jj < nj) {
            const int2 t = se[b0 + jj];
            s = t.x;
            w = __int_as_float(t.y);
            const float4* qp = (const float4*)(Q + (size_t)s * 128 + h * 32);
            float dot = 0.f;
#pragma unroll
            for (int i = 0; i < 8; ++i) {
                const float4 q = qp[i];
                const float4 k = *(const float4*)&Ksh[wid][h][i * 4];
                dot += q.x * k.x + q.y * k.y + q.z * k.z + q.w * k.w;
            }
            float bb = fmaf(w, weH, beH);
            bb = (bb > 0.f) ? bb : NEG_SLOPE * bb;
            p = __expf(fmaf(dot, 0.17677669529663687f, bb));
        }
        degacc += p;
        const float coef = p * w;

        if (nj == 16) {
#pragma unroll
            for (int j = 0; j < 16; ++j) {
                const float cj = __shfl(coef, j * 4 + hd);
                const int   sj = __shfl(s,    j * 4);
                const float2 v = Vv2[(size_t)sj * 64 + l];
                ax = fmaf(cj, v.x, ax);
                ay = fmaf(cj, v.y, ay);
            }
        } else {
            for (int j = 0; j < nj; ++j) {
                const float cj = __shfl(coef, j * 4 + hd);
                const int   sj = __shfl(s,    j * 4);
                const float2 v = Vv2[(size_t)sj * 64 + l];
                ax = fmaf(cj, v.x, ax);
                ay = fmaf(cj, v.y, ay);
            }
        }
    }

    float d = degacc;
    d += __shfl_xor(d, 4);
    d += __shfl_xor(d, 8);
    d += __shfl_xor(d, 16);
    d += __shfl_xor(d, 32);
    const float deg = __shfl(d, hd);
    const float inv = 1.0f / (deg + 1e-16f);

    *(float2*)(accum + (size_t)node * 128 + l * 2) =
        make_float2(ax * inv, ay * inv);
}

// ---------------------------------------------------------------------------
extern "C" void kernel_launch(void* const* d_in, const int* in_sizes, int n_in,
                              void* d_out, int out_size, void* d_ws, size_t ws_size,
                              hipStream_t stream)
{
    const float* h   = (const float*)d_in[0];
    const int*   ei  = (const int*)  d_in[1];
    const float* ew  = (const float*)d_in[2];
    const float* Wq  = (const float*)d_in[3];
    const float* bq  = (const float*)d_in[4];
    const float* Wk  = (const float*)d_in[5];
    const float* bk  = (const float*)d_in[6];
    const float* Wv  = (const float*)d_in[7];
    const float* bv  = (const float*)d_in[8];
    const float* Wo  = (const float*)d_in[9];
    const float* bo  = (const float*)d_in[10];
    const float* Wei = (const float*)d_in[11];
    const float* bei = (const float*)d_in[12];

    const int V = in_sizes[0] / 128;
    const int E = in_sizes[2];
    const int* src = ei;
    const int* tgt = ei + E;

    // workspace layout
    float* Q     = (float*)d_ws;
    float* Km    = Q  + (size_t)V * 128;
    float* Vm    = Km + (size_t)V * 128;
    float* accum = Vm + (size_t)V * 128;
    unsigned short* Wsp = (unsigned short*)(accum + (size_t)V * 128);
    unsigned short* WthQ = Wsp;               // 8 x 16384 bf16 = 256 KB
    unsigned short* WtlQ = Wsp + 16384;
    unsigned short* WthK = Wsp + 2 * 16384;
    unsigned short* WtlK = Wsp + 3 * 16384;
    unsigned short* WthV = Wsp + 4 * 16384;
    unsigned short* WtlV = Wsp + 5 * 16384;
    unsigned short* WthO = Wsp + 6 * 16384;
    unsigned short* WtlO = Wsp + 7 * 16384;
    int2*  se    = (int2*)(Wsp + 8 * 16384);
    int*   cnt   = (int*)(se + E);
    int*   offs  = cnt  + V;
    int*   fill  = offs + V + 1;
    int*   bsums = fill + V;

    hipMemsetAsync(cnt, 0, (size_t)V * sizeof(int), stream);

    // pre-split + transpose the 4 weight matrices (tiny)
    wsplit<<<64, 256, 0, stream>>>(Wq, WthQ, WtlQ);
    wsplit<<<64, 256, 0, stream>>>(Wk, WthK, WtlK);
    wsplit<<<64, 256, 0, stream>>>(Wv, WthV, WtlV);
    wsplit<<<64, 256, 0, stream>>>(Wo, WthO, WtlO);

    const int mfGrid = (V + 63) / 64;
    gemm_mfma<<<dim3(mfGrid, 3), 256, 0, stream>>>(
        h, WthQ, WtlQ, WthK, WtlK, WthV, WtlV,
        bq, bk, bv, Q, Km, Vm, V, 0);

    count_tgt<<<(E + 255) / 256, 256, 0, stream>>>(tgt, cnt, E);
    const int nb = (V + 1023) / 1024;
    scan1<<<nb, 256, 0, stream>>>(cnt, offs, bsums, V);
    scan2<<<1, 64, 0, stream>>>(bsums, nb);
    scan3<<<(V + 255) / 256, 256, 0, stream>>>(offs, bsums, fill, V);
    scatter_edges<<<(E + 255) / 256, 256, 0, stream>>>(
        src, tgt, ew, fill, se, E);

    fused_agg<<<(V + 3) / 4, 256, 0, stream>>>(
        Q, Km, Vm, se, offs, fill, Wei, bei, accum, V);

    gemm_mfma<<<dim3(mfGrid, 1), 256, 0, stream>>>(
        accum, WthO, WtlO, WthO, WtlO, WthO, WtlO,
        bo, bo, bo, (float*)d_out, (float*)d_out, (float*)d_out, V, 1);
}